// Round 1
// baseline (1660.439 us; speedup 1.0000x reference)
//
#include <hip/hip_runtime.h>
#include <hip/hip_bf16.h>
#include <math.h>

// Problem constants
#define B_  64
#define T_  128
#define E_  300
#define H_  256      // hidden per direction
#define G4  1024     // 4*H
#define N2  2048     // both directions' gates
#define GG  512      // G = 2H
#define FH_ 256
#define NC_ 2

// ---------------------------------------------------------------------------
// K0: transpose w_hh (1024,256) -> wt[d][k][n] (2,256,1024) for coalesced
// per-step reads in the LSTM kernel.
// ---------------------------------------------------------------------------
__global__ void k_wt(const float* __restrict__ w_hh_f,
                     const float* __restrict__ w_hh_b,
                     float* __restrict__ wt) {
    int idx = blockIdx.x * 256 + threadIdx.x;   // 0 .. 2*256*1024-1
    int d = idx >> 18;                          // 262144 per direction
    int r = idx & 262143;
    int k = r >> 10;                            // 0..255
    int n = r & 1023;                           // 0..1023
    const float* w = d ? w_hh_b : w_hh_f;       // (1024,256) row-major
    wt[idx] = w[n * 256 + k];
}

// ---------------------------------------------------------------------------
// K1: fused gather + input projection GEMM.
// xproj[m][n] = sum_k glove[sentence[m]][k] * Wcat[n][k] + (b_ih+b_hh)[n]
// m in [0,8192) = b*T+t ; n in [0,2048): n<1024 fwd gates, else bwd gates.
// fp32, 64x64 tile, 256 threads, 4x4 micro-tile. Correctness-first.
// ---------------------------------------------------------------------------
#define BM 64
#define BN 64
#define BK 8
__global__ __launch_bounds__(256) void k_xproj(
    const int*   __restrict__ sentence,  // (8192,)
    const float* __restrict__ glove,     // (V,300)
    const float* __restrict__ w_ih_f,    // (1024,300)
    const float* __restrict__ w_ih_b,    // (1024,300)
    const float* __restrict__ b_ih_f, const float* __restrict__ b_hh_f,
    const float* __restrict__ b_ih_b, const float* __restrict__ b_hh_b,
    float* __restrict__ xproj)           // (8192,2048)
{
    __shared__ float As[BK][BM + 4];
    __shared__ float Bs[BK][BN + 4];
    const int tid = threadIdx.x;
    const int m0 = blockIdx.x * BM;
    const int n0 = blockIdx.y * BN;
    const int tx = tid & 15, ty = tid >> 4;
    const int ar = tid >> 3;   // 0..31 (row within tile for loads)
    const int ac = tid & 7;    // 0..7  (k within k-tile for loads)

    const float* arow0 = glove + (size_t)sentence[m0 + ar] * E_;
    const float* arow1 = glove + (size_t)sentence[m0 + ar + 32] * E_;
    const int nr0 = n0 + ar, nr1 = n0 + ar + 32;
    const float* brow0 = (nr0 < G4) ? (w_ih_f + (size_t)nr0 * E_)
                                    : (w_ih_b + (size_t)(nr0 - G4) * E_);
    const float* brow1 = (nr1 < G4) ? (w_ih_f + (size_t)nr1 * E_)
                                    : (w_ih_b + (size_t)(nr1 - G4) * E_);

    float acc[4][4] = {};
    for (int k0 = 0; k0 < E_; k0 += BK) {
        const int kk = k0 + ac;
        const bool kin = kk < E_;
        As[ac][ar]      = kin ? arow0[kk] : 0.f;
        As[ac][ar + 32] = kin ? arow1[kk] : 0.f;
        Bs[ac][ar]      = kin ? brow0[kk] : 0.f;
        Bs[ac][ar + 32] = kin ? brow1[kk] : 0.f;
        __syncthreads();
        #pragma unroll
        for (int k = 0; k < BK; ++k) {
            float ra[4], rb[4];
            #pragma unroll
            for (int i = 0; i < 4; ++i) ra[i] = As[k][ty * 4 + i];
            #pragma unroll
            for (int j = 0; j < 4; ++j) rb[j] = Bs[k][tx * 4 + j];
            #pragma unroll
            for (int i = 0; i < 4; ++i)
                #pragma unroll
                for (int j = 0; j < 4; ++j) acc[i][j] += ra[i] * rb[j];
        }
        __syncthreads();
    }
    #pragma unroll
    for (int i = 0; i < 4; ++i) {
        const int m = m0 + ty * 4 + i;
        #pragma unroll
        for (int j = 0; j < 4; ++j) {
            const int n = n0 + tx * 4 + j;
            const float bias = (n < G4) ? (b_ih_f[n] + b_hh_f[n])
                                        : (b_ih_b[n - G4] + b_hh_b[n - G4]);
            xproj[(size_t)m * N2 + n] = acc[i][j] + bias;
        }
    }
}

// ---------------------------------------------------------------------------
// K2: BiLSTM recurrence + masked sum over time (fuses the GAT sum).
// One block per (direction, batch-pair): 64 blocks x 1024 threads.
// No inter-block sync ever. h in LDS, c and running-sum in registers.
// Writes S (64,512): [:,0:256] = fwd masked sum, [:,256:512] = bwd.
// ---------------------------------------------------------------------------
__global__ __launch_bounds__(1024) void k_lstm(
    const float* __restrict__ xproj,    // (64,128,2048)
    const float* __restrict__ wt,       // (2,256,1024)
    const int*   __restrict__ text_len, // (64,)
    float* __restrict__ S)              // (64,512)
{
    __shared__ float h[2][H_];
    __shared__ float gbuf[2][G4];
    const int tid = threadIdx.x;
    const int d   = blockIdx.x & 1;
    const int b0  = (blockIdx.x >> 1) * 2;
    const float* W = wt + (size_t)d * (H_ * G4);
    const int bb = tid >> 8;      // meaningful for tid<512: 0/1
    const int j  = tid & 255;

    float c = 0.f, s = 0.f;
    if (tid < 512) h[bb][j] = 0.f;
    __syncthreads();
    const int len0 = text_len[b0], len1 = text_len[b0 + 1];

    for (int t = 0; t < T_; ++t) {
        const int tt = d ? (T_ - 1 - t) : t;
        // Phase A: all 1024 threads compute gate n=tid for both batch rows.
        const int n = tid;
        float a0 = xproj[((size_t)b0 * T_ + tt) * N2 + d * G4 + n];
        float a1 = xproj[((size_t)(b0 + 1) * T_ + tt) * N2 + d * G4 + n];
        #pragma unroll 8
        for (int k = 0; k < H_; ++k) {
            const float w = W[k * G4 + n];   // coalesced across tid
            a0 += w * h[0][k];               // LDS broadcast
            a1 += w * h[1][k];
        }
        gbuf[0][n] = a0;
        gbuf[1][n] = a1;
        __syncthreads();
        // Phase B: threads 0..511 update (b,j) cell state.
        if (tid < 512) {
            const float gi = gbuf[bb][j];
            const float gf = gbuf[bb][j + 256];
            const float gg = gbuf[bb][j + 512];
            const float go = gbuf[bb][j + 768];
            const float i_ = 1.f / (1.f + __expf(-gi));
            const float f_ = 1.f / (1.f + __expf(-gf));
            const float g_ = tanhf(gg);
            const float o_ = 1.f / (1.f + __expf(-go));
            c = f_ * c + i_ * g_;
            const float hn = o_ * tanhf(c);
            const int len = bb ? len1 : len0;
            if (tt < len) s += hn;           // fused masked GAT sum
            h[bb][j] = hn;
        }
        __syncthreads();
    }
    if (tid < 512)
        S[(size_t)(b0 + bb) * GG + d * H_ + j] = s;
}

// ---------------------------------------------------------------------------
// K3: head. One block per batch row.
// gat = relu(S @ gat_w.T + gat_b*len); fc1,fc2 relu; fcf logits.
// ---------------------------------------------------------------------------
__global__ __launch_bounds__(256) void k_head(
    const float* __restrict__ S,        // (64,512)
    const int*   __restrict__ text_len,
    const float* __restrict__ gat_w, const float* __restrict__ gat_b,
    const float* __restrict__ fc1_w, const float* __restrict__ fc1_b,
    const float* __restrict__ fc2_w, const float* __restrict__ fc2_b,
    const float* __restrict__ fcf_w, const float* __restrict__ fcf_b,
    float* __restrict__ out)            // (64,2)
{
    __shared__ float sb[GG];
    __shared__ float x1[GG];
    __shared__ float x2[FH_];
    __shared__ float x3[FH_];
    const int b = blockIdx.x, tid = threadIdx.x;
    sb[tid]       = S[(size_t)b * GG + tid];
    sb[tid + 256] = S[(size_t)b * GG + tid + 256];
    __syncthreads();
    const float lenf = (float)text_len[b];
    #pragma unroll
    for (int r = 0; r < 2; ++r) {
        const int n = tid + r * 256;
        float acc = gat_b[n] * lenf;     // masked-summed bias = b * len
        const float* w = gat_w + (size_t)n * GG;
        for (int k = 0; k < GG; ++k) acc += sb[k] * w[k];
        x1[n] = fmaxf(acc, 0.f);
    }
    __syncthreads();
    {
        float acc = fc1_b[tid];
        const float* w = fc1_w + (size_t)tid * GG;
        for (int k = 0; k < GG; ++k) acc += x1[k] * w[k];
        x2[tid] = fmaxf(acc, 0.f);
    }
    __syncthreads();
    {
        float acc = fc2_b[tid];
        const float* w = fc2_w + (size_t)tid * FH_;
        for (int k = 0; k < FH_; ++k) acc += x2[k] * w[k];
        x3[tid] = fmaxf(acc, 0.f);
    }
    __syncthreads();
    if (tid < NC_) {
        float acc = fcf_b[tid];
        const float* w = fcf_w + (size_t)tid * FH_;
        for (int k = 0; k < FH_; ++k) acc += x3[k] * w[k];
        out[b * NC_ + tid] = acc;
    }
}

// ---------------------------------------------------------------------------
extern "C" void kernel_launch(void* const* d_in, const int* in_sizes, int n_in,
                              void* d_out, int out_size, void* d_ws, size_t ws_size,
                              hipStream_t stream) {
    const int*   sentence = (const int*)  d_in[0];
    const int*   text_len = (const int*)  d_in[4];
    const float* glove    = (const float*)d_in[10];
    const float* w_ih_f   = (const float*)d_in[11];
    const float* w_hh_f   = (const float*)d_in[12];
    const float* b_ih_f   = (const float*)d_in[13];
    const float* b_hh_f   = (const float*)d_in[14];
    const float* w_ih_b   = (const float*)d_in[15];
    const float* w_hh_b   = (const float*)d_in[16];
    const float* b_ih_b   = (const float*)d_in[17];
    const float* b_hh_b   = (const float*)d_in[18];
    const float* gat_w    = (const float*)d_in[19];
    const float* gat_b    = (const float*)d_in[20];
    const float* fc1_w    = (const float*)d_in[21];
    const float* fc1_b    = (const float*)d_in[22];
    const float* fc2_w    = (const float*)d_in[23];
    const float* fc2_b    = (const float*)d_in[24];
    const float* fcf_w    = (const float*)d_in[25];
    const float* fcf_b    = (const float*)d_in[26];
    float* out = (float*)d_out;

    // Workspace layout (floats): wt | xproj | S
    float* ws    = (float*)d_ws;
    float* wt    = ws;                              // 2*256*1024   = 524288
    float* xproj = ws + 524288;                     // 8192*2048    = 16777216
    float* S     = xproj + 16777216;                // 64*512       = 32768

    k_wt<<<2048, 256, 0, stream>>>(w_hh_f, w_hh_b, wt);
    dim3 g1(8192 / BM, N2 / BN);
    k_xproj<<<g1, 256, 0, stream>>>(sentence, glove, w_ih_f, w_ih_b,
                                    b_ih_f, b_hh_f, b_ih_b, b_hh_b, xproj);
    k_lstm<<<64, 1024, 0, stream>>>(xproj, wt, text_len, S);
    k_head<<<64, 256, 0, stream>>>(S, text_len, gat_w, gat_b,
                                   fc1_w, fc1_b, fc2_w, fc2_b,
                                   fcf_w, fcf_b, out);
}

// Round 2
// 1655.299 us; speedup vs baseline: 1.0031x; 1.0031x over previous
//
#include <hip/hip_runtime.h>
#include <hip/hip_bf16.h>
#include <math.h>

// Problem constants
#define B_  64
#define T_  128
#define E_  300
#define H_  256      // hidden per direction
#define G4  1024     // 4*H
#define N2  2048     // both directions' gates
#define GG  512      // G = 2H
#define FH_ 256
#define NC_ 2

typedef __attribute__((ext_vector_type(8))) short short8;
typedef __attribute__((ext_vector_type(4))) float f32x4;
typedef unsigned short ushort_t;

// ---------------------------------------------------------------------------
// K0: pre-shuffle w_hh (1024,256) f32 -> bf16 MFMA B-fragment streaming order.
// Layout: [d][wave(16)][ks(8)][nt(4)][lane(64)][j(8)] so the LSTM hot loop
// reads one linear dwordx4 per (ks,nt) per lane.
// B-frag for mfma_f32_16x16x32_bf16: lane holds B[k=quad*8+j][n=lane&15]
// with n = wave*64 + nt*16 + (lane&15), k = ks*32 + (lane>>4)*8 + j.
// w_hh is (N=1024 gates, K=256) row-major == B^T, so rows are K-contiguous.
// ---------------------------------------------------------------------------
__global__ void k_wshuf(const float* __restrict__ w_hh_f,
                        const float* __restrict__ w_hh_b,
                        ushort_t* __restrict__ wshuf) {
    const int t = blockIdx.x * 256 + threadIdx.x;   // 0..65535
    const int d  = t >> 15;
    const int w  = (t >> 11) & 15;
    const int ks = (t >> 8) & 7;
    const int nt = (t >> 6) & 3;
    const int l  = t & 63;
    const int n  = w * 64 + nt * 16 + (l & 15);
    const int k0 = ks * 32 + ((l >> 4) << 3);
    const float* src = (d ? w_hh_b : w_hh_f) + (size_t)n * 256 + k0;
    ushort_t o[8];
    #pragma unroll
    for (int j = 0; j < 8; ++j) {
        __hip_bfloat16 b = __float2bfloat16(src[j]);
        o[j] = __builtin_bit_cast(ushort_t, b);
    }
    uint4 pk;
    pk.x = (unsigned)o[0] | ((unsigned)o[1] << 16);
    pk.y = (unsigned)o[2] | ((unsigned)o[3] << 16);
    pk.z = (unsigned)o[4] | ((unsigned)o[5] << 16);
    pk.w = (unsigned)o[6] | ((unsigned)o[7] << 16);
    *(uint4*)(wshuf + (size_t)t * 8) = pk;
}

// ---------------------------------------------------------------------------
// K1: fused gather + input projection GEMM (unchanged from R1).
// ---------------------------------------------------------------------------
#define BM 64
#define BN 64
#define BK 8
__global__ __launch_bounds__(256) void k_xproj(
    const int*   __restrict__ sentence,
    const float* __restrict__ glove,
    const float* __restrict__ w_ih_f,
    const float* __restrict__ w_ih_b,
    const float* __restrict__ b_ih_f, const float* __restrict__ b_hh_f,
    const float* __restrict__ b_ih_b, const float* __restrict__ b_hh_b,
    float* __restrict__ xproj)
{
    __shared__ float As[BK][BM + 4];
    __shared__ float Bs[BK][BN + 4];
    const int tid = threadIdx.x;
    const int m0 = blockIdx.x * BM;
    const int n0 = blockIdx.y * BN;
    const int tx = tid & 15, ty = tid >> 4;
    const int ar = tid >> 3;
    const int ac = tid & 7;

    const float* arow0 = glove + (size_t)sentence[m0 + ar] * E_;
    const float* arow1 = glove + (size_t)sentence[m0 + ar + 32] * E_;
    const int nr0 = n0 + ar, nr1 = n0 + ar + 32;
    const float* brow0 = (nr0 < G4) ? (w_ih_f + (size_t)nr0 * E_)
                                    : (w_ih_b + (size_t)(nr0 - G4) * E_);
    const float* brow1 = (nr1 < G4) ? (w_ih_f + (size_t)nr1 * E_)
                                    : (w_ih_b + (size_t)(nr1 - G4) * E_);

    float acc[4][4] = {};
    for (int k0 = 0; k0 < E_; k0 += BK) {
        const int kk = k0 + ac;
        const bool kin = kk < E_;
        As[ac][ar]      = kin ? arow0[kk] : 0.f;
        As[ac][ar + 32] = kin ? arow1[kk] : 0.f;
        Bs[ac][ar]      = kin ? brow0[kk] : 0.f;
        Bs[ac][ar + 32] = kin ? brow1[kk] : 0.f;
        __syncthreads();
        #pragma unroll
        for (int k = 0; k < BK; ++k) {
            float ra[4], rb[4];
            #pragma unroll
            for (int i = 0; i < 4; ++i) ra[i] = As[k][ty * 4 + i];
            #pragma unroll
            for (int j = 0; j < 4; ++j) rb[j] = Bs[k][tx * 4 + j];
            #pragma unroll
            for (int i = 0; i < 4; ++i)
                #pragma unroll
                for (int j = 0; j < 4; ++j) acc[i][j] += ra[i] * rb[j];
        }
        __syncthreads();
    }
    #pragma unroll
    for (int i = 0; i < 4; ++i) {
        const int m = m0 + ty * 4 + i;
        #pragma unroll
        for (int j = 0; j < 4; ++j) {
            const int n = n0 + tx * 4 + j;
            const float bias = (n < G4) ? (b_ih_f[n] + b_hh_f[n])
                                        : (b_ih_b[n - G4] + b_hh_b[n - G4]);
            xproj[(size_t)m * N2 + n] = acc[i][j] + bias;
        }
    }
}

// ---------------------------------------------------------------------------
// K2: BiLSTM via MFMA. 8 blocks = (2 dirs x 4 groups of 16 batches).
// 1024 threads = 16 waves; wave w owns gates [w*64, w*64+64) (4 n-tiles).
// Per step: gates = h(16,256)bf16 @ W(256,1024)bf16 via 16x16x32 MFMA,
// W streamed from L2 in pre-shuffled frag order; then per-thread cell update
// (+xproj, nonlinearities, masked GAT sum, bf16 h write-back).
// ---------------------------------------------------------------------------
__global__ __launch_bounds__(1024) void k_lstm_mfma(
    const float*    __restrict__ xproj,    // (64,128,2048) f32
    const ushort_t* __restrict__ wshuf,    // (2,16,8,4,64,8) bf16 frags
    const int*      __restrict__ text_len,
    float*          __restrict__ S)        // (64,512)
{
    __shared__ ushort_t hlds[16][264];     // h bf16, row pad +8 (2-way = free)
    __shared__ float    gbuf[16][1028];    // gate accum f32, row pad +4

    const int tid  = threadIdx.x;
    const int d    = blockIdx.x & 1;
    const int b0   = (blockIdx.x >> 1) * 16;
    const int wave = tid >> 6, lane = tid & 63;
    const int quad = lane >> 4, l15 = lane & 15;

    // phase-B cell assignment: batch m_c, hidden j0..j0+3
    const int m_c = tid >> 6;
    const int j0  = (tid & 63) * 4;
    const int lenm = text_len[b0 + m_c];

    for (int i = tid; i < 16 * 264; i += 1024) ((ushort_t*)hlds)[i] = 0;
    float c[4] = {0.f, 0.f, 0.f, 0.f};
    float s[4] = {0.f, 0.f, 0.f, 0.f};
    __syncthreads();

    const short8* wp = (const short8*)(wshuf + (size_t)(d * 16 + wave) * 16384);
    const ushort_t* arow = &hlds[l15][0];

    for (int t = 0; t < T_; ++t) {
        const int tt = d ? (T_ - 1 - t) : t;
        // ---- phase A: MFMA h @ W ----
        short8 af[8];
        #pragma unroll
        for (int ks = 0; ks < 8; ++ks)
            af[ks] = *(const short8*)(arow + ks * 32 + quad * 8);
        f32x4 acc[4] = {};
        #pragma unroll
        for (int ks = 0; ks < 8; ++ks) {
            #pragma unroll
            for (int nt = 0; nt < 4; ++nt) {
                short8 bfr = wp[(ks * 4 + nt) * 64 + lane];
                acc[nt] = __builtin_amdgcn_mfma_f32_16x16x32_bf16(
                    af[ks], bfr, acc[nt], 0, 0, 0);
            }
        }
        // C layout (m89): row(batch)=quad*4+r, col(gate)=lane&15
        #pragma unroll
        for (int nt = 0; nt < 4; ++nt)
            #pragma unroll
            for (int r = 0; r < 4; ++r)
                gbuf[quad * 4 + r][wave * 64 + nt * 16 + l15] = acc[nt][r];
        __syncthreads();
        // ---- phase B: nonlinearity + cell update + masked sum ----
        const float* xp = xproj + ((size_t)(b0 + m_c) * T_ + tt) * N2 + d * G4;
        float4 xi = *(const float4*)(xp + j0);
        float4 xf = *(const float4*)(xp + j0 + 256);
        float4 xg = *(const float4*)(xp + j0 + 512);
        float4 xo = *(const float4*)(xp + j0 + 768);
        float4 bi = *(const float4*)&gbuf[m_c][j0];
        float4 bf = *(const float4*)&gbuf[m_c][j0 + 256];
        float4 bg = *(const float4*)&gbuf[m_c][j0 + 512];
        float4 bo = *(const float4*)&gbuf[m_c][j0 + 768];
        const float* xiP = (const float*)&xi; const float* biP = (const float*)&bi;
        const float* xfP = (const float*)&xf; const float* bfP = (const float*)&bf;
        const float* xgP = (const float*)&xg; const float* bgP = (const float*)&bg;
        const float* xoP = (const float*)&xo; const float* boP = (const float*)&bo;
        const bool in_len = (tt < lenm);
        ushort_t hb[4];
        #pragma unroll
        for (int u = 0; u < 4; ++u) {
            const float gi = xiP[u] + biP[u];
            const float gf = xfP[u] + bfP[u];
            const float gg = xgP[u] + bgP[u];
            const float go = xoP[u] + boP[u];
            const float i_ = 1.f / (1.f + __expf(-gi));
            const float f_ = 1.f / (1.f + __expf(-gf));
            const float g_ = tanhf(gg);
            const float o_ = 1.f / (1.f + __expf(-go));
            c[u] = f_ * c[u] + i_ * g_;
            const float hn = o_ * tanhf(c[u]);
            if (in_len) s[u] += hn;
            __hip_bfloat16 hbf = __float2bfloat16(hn);
            hb[u] = __builtin_bit_cast(ushort_t, hbf);
        }
        *(ushort4*)&hlds[m_c][j0] = make_ushort4(hb[0], hb[1], hb[2], hb[3]);
        __syncthreads();
    }
    #pragma unroll
    for (int u = 0; u < 4; ++u)
        S[(size_t)(b0 + m_c) * GG + d * H_ + j0 + u] = s[u];
}

// ---------------------------------------------------------------------------
// K3: head (unchanged from R1).
// ---------------------------------------------------------------------------
__global__ __launch_bounds__(256) void k_head(
    const float* __restrict__ S,
    const int*   __restrict__ text_len,
    const float* __restrict__ gat_w, const float* __restrict__ gat_b,
    const float* __restrict__ fc1_w, const float* __restrict__ fc1_b,
    const float* __restrict__ fc2_w, const float* __restrict__ fc2_b,
    const float* __restrict__ fcf_w, const float* __restrict__ fcf_b,
    float* __restrict__ out)
{
    __shared__ float sb[GG];
    __shared__ float x1[GG];
    __shared__ float x2[FH_];
    __shared__ float x3[FH_];
    const int b = blockIdx.x, tid = threadIdx.x;
    sb[tid]       = S[(size_t)b * GG + tid];
    sb[tid + 256] = S[(size_t)b * GG + tid + 256];
    __syncthreads();
    const float lenf = (float)text_len[b];
    #pragma unroll
    for (int r = 0; r < 2; ++r) {
        const int n = tid + r * 256;
        float acc = gat_b[n] * lenf;
        const float* w = gat_w + (size_t)n * GG;
        for (int k = 0; k < GG; ++k) acc += sb[k] * w[k];
        x1[n] = fmaxf(acc, 0.f);
    }
    __syncthreads();
    {
        float acc = fc1_b[tid];
        const float* w = fc1_w + (size_t)tid * GG;
        for (int k = 0; k < GG; ++k) acc += x1[k] * w[k];
        x2[tid] = fmaxf(acc, 0.f);
    }
    __syncthreads();
    {
        float acc = fc2_b[tid];
        const float* w = fc2_w + (size_t)tid * FH_;
        for (int k = 0; k < FH_; ++k) acc += x2[k] * w[k];
        x3[tid] = fmaxf(acc, 0.f);
    }
    __syncthreads();
    if (tid < NC_) {
        float acc = fcf_b[tid];
        const float* w = fcf_w + (size_t)tid * FH_;
        for (int k = 0; k < FH_; ++k) acc += x3[k] * w[k];
        out[b * NC_ + tid] = acc;
    }
}

// ---------------------------------------------------------------------------
extern "C" void kernel_launch(void* const* d_in, const int* in_sizes, int n_in,
                              void* d_out, int out_size, void* d_ws, size_t ws_size,
                              hipStream_t stream) {
    const int*   sentence = (const int*)  d_in[0];
    const int*   text_len = (const int*)  d_in[4];
    const float* glove    = (const float*)d_in[10];
    const float* w_ih_f   = (const float*)d_in[11];
    const float* w_hh_f   = (const float*)d_in[12];
    const float* b_ih_f   = (const float*)d_in[13];
    const float* b_hh_f   = (const float*)d_in[14];
    const float* w_ih_b   = (const float*)d_in[15];
    const float* w_hh_b   = (const float*)d_in[16];
    const float* b_ih_b   = (const float*)d_in[17];
    const float* b_hh_b   = (const float*)d_in[18];
    const float* gat_w    = (const float*)d_in[19];
    const float* gat_b    = (const float*)d_in[20];
    const float* fc1_w    = (const float*)d_in[21];
    const float* fc1_b    = (const float*)d_in[22];
    const float* fc2_w    = (const float*)d_in[23];
    const float* fc2_b    = (const float*)d_in[24];
    const float* fcf_w    = (const float*)d_in[25];
    const float* fcf_b    = (const float*)d_in[26];
    float* out = (float*)d_out;

    // Workspace layout: wshuf bf16 (1 MB) | xproj f32 (64 MB) | S
    ushort_t* wshuf = (ushort_t*)d_ws;                       // 524288 ushort
    float* xproj = (float*)((char*)d_ws + (1 << 20));        // 8192*2048 f32
    float* S     = xproj + (size_t)8192 * 2048;              // 64*512 f32

    k_wshuf<<<256, 256, 0, stream>>>(w_hh_f, w_hh_b, wshuf);
    dim3 g1(8192 / BM, N2 / BN);
    k_xproj<<<g1, 256, 0, stream>>>(sentence, glove, w_ih_f, w_ih_b,
                                    b_ih_f, b_hh_f, b_ih_b, b_hh_b, xproj);
    k_lstm_mfma<<<8, 1024, 0, stream>>>(xproj, wshuf, text_len, S);
    k_head<<<64, 256, 0, stream>>>(S, text_len, gat_w, gat_b,
                                   fc1_w, fc1_b, fc2_w, fc2_b,
                                   fcf_w, fcf_b, out);
}

// Round 3
// 1090.307 us; speedup vs baseline: 1.5229x; 1.5182x over previous
//
#include <hip/hip_runtime.h>
#include <hip/hip_bf16.h>
#include <math.h>

// Problem constants
#define B_  64
#define T_  128
#define E_  300
#define H_  256      // hidden per direction
#define G4  1024     // 4*H
#define N2  2048     // both directions' gates
#define GG  512      // G = 2H
#define FH_ 256
#define NC_ 2

typedef __attribute__((ext_vector_type(8))) short short8;
typedef __attribute__((ext_vector_type(4))) float f32x4;
typedef unsigned short ushort_t;

static __device__ __forceinline__ ushort_t bf16bits(float x) {
    __hip_bfloat16 b = __float2bfloat16(x);
    return __builtin_bit_cast(ushort_t, b);
}

// ---------------------------------------------------------------------------
// K_init: zero the inter-block h-exchange buffers and step counters.
// Harness re-poisons d_ws to 0xAA before every timed launch.
// hbuf: 2 parities x 8 groups x (16 batch x 256 k) bf16  = 131072 B
// cnt:  8 groups x 128 steps int                          = 4096 B
// ---------------------------------------------------------------------------
#define HBUF_US   (2 * 8 * 4096)          // ushort count = 65536
#define INIT_U32  ((131072 + 4096) / 4)   // 33792 dwords
__global__ void k_init(unsigned* __restrict__ p) {
    int i = blockIdx.x * 256 + threadIdx.x;
    if (i < INIT_U32) p[i] = 0;
}

// ---------------------------------------------------------------------------
// K1: fused gather + input projection GEMM (fp32; unchanged).
// ---------------------------------------------------------------------------
#define BM 64
#define BN 64
#define BK 8
__global__ __launch_bounds__(256) void k_xproj(
    const int*   __restrict__ sentence,
    const float* __restrict__ glove,
    const float* __restrict__ w_ih_f,
    const float* __restrict__ w_ih_b,
    const float* __restrict__ b_ih_f, const float* __restrict__ b_hh_f,
    const float* __restrict__ b_ih_b, const float* __restrict__ b_hh_b,
    float* __restrict__ xproj)
{
    __shared__ float As[BK][BM + 4];
    __shared__ float Bs[BK][BN + 4];
    const int tid = threadIdx.x;
    const int m0 = blockIdx.x * BM;
    const int n0 = blockIdx.y * BN;
    const int tx = tid & 15, ty = tid >> 4;
    const int ar = tid >> 3;
    const int ac = tid & 7;

    const float* arow0 = glove + (size_t)sentence[m0 + ar] * E_;
    const float* arow1 = glove + (size_t)sentence[m0 + ar + 32] * E_;
    const int nr0 = n0 + ar, nr1 = n0 + ar + 32;
    const float* brow0 = (nr0 < G4) ? (w_ih_f + (size_t)nr0 * E_)
                                    : (w_ih_b + (size_t)(nr0 - G4) * E_);
    const float* brow1 = (nr1 < G4) ? (w_ih_f + (size_t)nr1 * E_)
                                    : (w_ih_b + (size_t)(nr1 - G4) * E_);

    float acc[4][4] = {};
    for (int k0 = 0; k0 < E_; k0 += BK) {
        const int kk = k0 + ac;
        const bool kin = kk < E_;
        As[ac][ar]      = kin ? arow0[kk] : 0.f;
        As[ac][ar + 32] = kin ? arow1[kk] : 0.f;
        Bs[ac][ar]      = kin ? brow0[kk] : 0.f;
        Bs[ac][ar + 32] = kin ? brow1[kk] : 0.f;
        __syncthreads();
        #pragma unroll
        for (int k = 0; k < BK; ++k) {
            float ra[4], rb[4];
            #pragma unroll
            for (int i = 0; i < 4; ++i) ra[i] = As[k][ty * 4 + i];
            #pragma unroll
            for (int j = 0; j < 4; ++j) rb[j] = Bs[k][tx * 4 + j];
            #pragma unroll
            for (int i = 0; i < 4; ++i)
                #pragma unroll
                for (int j = 0; j < 4; ++j) acc[i][j] += ra[i] * rb[j];
        }
        __syncthreads();
    }
    #pragma unroll
    for (int i = 0; i < 4; ++i) {
        const int m = m0 + ty * 4 + i;
        #pragma unroll
        for (int j = 0; j < 4; ++j) {
            const int n = n0 + tx * 4 + j;
            const float bias = (n < G4) ? (b_ih_f[n] + b_hh_f[n])
                                        : (b_ih_b[n - G4] + b_hh_b[n - G4]);
            xproj[(size_t)m * N2 + n] = acc[i][j] + bias;
        }
    }
}

// ---------------------------------------------------------------------------
// K2: BiLSTM, W register-resident, gate-dim split across 8 CUs per group.
// 64 blocks x 256 threads. group g = blockIdx&7 (same XCD under round-robin),
// slice = blockIdx>>3. group = (dir d = g&1, batches b0 = (g>>1)*16).
// Slice owns h cells [j0, j0+32): gate columns {q*256 + j0 .. +31 : q=0..3}.
// Wave w (=gate q) holds its W B-frags in 64 VGPRs (loaded once, bf16).
// Per step: MFMA h(16,256)@Wslice -> gates(16,128); LDS exchange; cell
// update (+xproj, masked GAT sum); h bf16 -> global hbuf (double-buffered);
// device-scope release counter; spin-acquire on previous step's counter.
// ---------------------------------------------------------------------------
__global__ __launch_bounds__(256, 1) void k_lstm_sync(
    const float* __restrict__ xproj,    // (64,128,2048) f32
    const float* __restrict__ w_hh_f,   // (1024,256) f32
    const float* __restrict__ w_hh_b,
    const int*   __restrict__ text_len,
    ushort_t*    __restrict__ hbuf,     // (2,8,16,256) bf16
    int*         __restrict__ cnt,      // (8,128)
    float*       __restrict__ S)        // (64,512)
{
    __shared__ float gLDS[4 * 16 * 33];   // [gate][batch][cell+pad]

    const int tid   = threadIdx.x;
    const int g     = blockIdx.x & 7;
    const int slice = blockIdx.x >> 3;
    const int d     = g & 1;
    const int b0    = (g >> 1) * 16;
    const int j0    = slice * 32;
    const int wave  = tid >> 6, lane = tid & 63;
    const int quad  = lane >> 4, l15 = lane & 15;

    const float* whh = d ? w_hh_b : w_hh_f;
    int* cnt_g = cnt + g * T_;

    // ---- preload W B-frags into registers (once) ----
    short8 wfrag[2][8];
    #pragma unroll
    for (int u = 0; u < 2; ++u) {
        const int n = wave * 256 + j0 + u * 16 + l15;
        #pragma unroll
        for (int ks = 0; ks < 8; ++ks) {
            const float* p = whh + (size_t)n * 256 + ks * 32 + quad * 8;
            float4 lo = *(const float4*)p;
            float4 hi = *(const float4*)(p + 4);
            short8 f;
            f[0] = (short)bf16bits(lo.x); f[1] = (short)bf16bits(lo.y);
            f[2] = (short)bf16bits(lo.z); f[3] = (short)bf16bits(lo.w);
            f[4] = (short)bf16bits(hi.x); f[5] = (short)bf16bits(hi.y);
            f[6] = (short)bf16bits(hi.z); f[7] = (short)bf16bits(hi.w);
            wfrag[u][ks] = f;
        }
    }

    // cell-update assignment: batch mb, cell pair c0,c0+1
    const int mb = tid >> 4;
    const int c0 = (tid & 15) * 2;
    const int lenm = text_len[b0 + mb];
    float cst0 = 0.f, cst1 = 0.f, s0 = 0.f, s1 = 0.f;

    for (int t = 0; t < T_; ++t) {
        const int tt = d ? (T_ - 1 - t) : t;
        // issue xproj loads BEFORE the spin (independent of h) to hide HBM
        const float* xp = xproj + ((size_t)(b0 + mb) * T_ + tt) * N2 + d * G4 + j0;
        float2 xi = *(const float2*)(xp + c0);
        float2 xf = *(const float2*)(xp + 256 + c0);
        float2 xg = *(const float2*)(xp + 512 + c0);
        float2 xo = *(const float2*)(xp + 768 + c0);

        if (t > 0 && tid == 0) {
            while (__hip_atomic_load(&cnt_g[t - 1], __ATOMIC_ACQUIRE,
                                     __HIP_MEMORY_SCOPE_AGENT) < 8)
                __builtin_amdgcn_s_sleep(1);
        }
        __syncthreads();

        // ---- A-frags from hbuf[t&1] ----
        const ushort_t* hin = hbuf + (size_t)(t & 1) * 32768 + g * 4096;
        short8 af[8];
        #pragma unroll
        for (int ks = 0; ks < 8; ++ks)
            af[ks] = *(const short8*)(hin + l15 * 256 + ks * 32 + quad * 8);
        f32x4 acc[2] = {};
        #pragma unroll
        for (int ks = 0; ks < 8; ++ks) {
            acc[0] = __builtin_amdgcn_mfma_f32_16x16x32_bf16(
                af[ks], wfrag[0][ks], acc[0], 0, 0, 0);
            acc[1] = __builtin_amdgcn_mfma_f32_16x16x32_bf16(
                af[ks], wfrag[1][ks], acc[1], 0, 0, 0);
        }
        // C layout: row(batch)=quad*4+r, col=l15
        #pragma unroll
        for (int u = 0; u < 2; ++u)
            #pragma unroll
            for (int r = 0; r < 4; ++r)
                gLDS[wave * 528 + (quad * 4 + r) * 33 + u * 16 + l15] = acc[u][r];
        __syncthreads();

        // ---- cell update for (mb, c0..c0+1) ----
        const int gb = mb * 33 + c0;
        const float gi0 = gLDS[gb],            gi1 = gLDS[gb + 1];
        const float gf0 = gLDS[528 + gb],      gf1 = gLDS[528 + gb + 1];
        const float gg0 = gLDS[1056 + gb],     gg1 = gLDS[1056 + gb + 1];
        const float go0 = gLDS[1584 + gb],     go1 = gLDS[1584 + gb + 1];
        const float i0 = 1.f / (1.f + __expf(-(xi.x + gi0)));
        const float i1 = 1.f / (1.f + __expf(-(xi.y + gi1)));
        const float f0 = 1.f / (1.f + __expf(-(xf.x + gf0)));
        const float f1 = 1.f / (1.f + __expf(-(xf.y + gf1)));
        const float gc0 = tanhf(xg.x + gg0);
        const float gc1 = tanhf(xg.y + gg1);
        const float o0 = 1.f / (1.f + __expf(-(xo.x + go0)));
        const float o1 = 1.f / (1.f + __expf(-(xo.y + go1)));
        cst0 = f0 * cst0 + i0 * gc0;
        cst1 = f1 * cst1 + i1 * gc1;
        const float h0 = o0 * tanhf(cst0);
        const float h1 = o1 * tanhf(cst1);
        if (tt < lenm) { s0 += h0; s1 += h1; }

        ushort_t* hout = hbuf + (size_t)((t + 1) & 1) * 32768 + g * 4096;
        unsigned hp = (unsigned)bf16bits(h0) | ((unsigned)bf16bits(h1) << 16);
        *(unsigned*)(hout + mb * 256 + j0 + c0) = hp;
        __syncthreads();   // drains vmcnt: h stores complete before flag
        if (tid == 0) {
            __threadfence();
            __hip_atomic_fetch_add(&cnt_g[t], 1, __ATOMIC_RELEASE,
                                   __HIP_MEMORY_SCOPE_AGENT);
        }
    }

    float2 sv; sv.x = s0; sv.y = s1;
    *(float2*)(S + (size_t)(b0 + mb) * GG + d * H_ + j0 + c0) = sv;
}

// ---------------------------------------------------------------------------
// K3: head (unchanged).
// ---------------------------------------------------------------------------
__global__ __launch_bounds__(256) void k_head(
    const float* __restrict__ S,
    const int*   __restrict__ text_len,
    const float* __restrict__ gat_w, const float* __restrict__ gat_b,
    const float* __restrict__ fc1_w, const float* __restrict__ fc1_b,
    const float* __restrict__ fc2_w, const float* __restrict__ fc2_b,
    const float* __restrict__ fcf_w, const float* __restrict__ fcf_b,
    float* __restrict__ out)
{
    __shared__ float sb[GG];
    __shared__ float x1[GG];
    __shared__ float x2[FH_];
    __shared__ float x3[FH_];
    const int b = blockIdx.x, tid = threadIdx.x;
    sb[tid]       = S[(size_t)b * GG + tid];
    sb[tid + 256] = S[(size_t)b * GG + tid + 256];
    __syncthreads();
    const float lenf = (float)text_len[b];
    #pragma unroll
    for (int r = 0; r < 2; ++r) {
        const int n = tid + r * 256;
        float acc = gat_b[n] * lenf;
        const float* w = gat_w + (size_t)n * GG;
        for (int k = 0; k < GG; ++k) acc += sb[k] * w[k];
        x1[n] = fmaxf(acc, 0.f);
    }
    __syncthreads();
    {
        float acc = fc1_b[tid];
        const float* w = fc1_w + (size_t)tid * GG;
        for (int k = 0; k < GG; ++k) acc += x1[k] * w[k];
        x2[tid] = fmaxf(acc, 0.f);
    }
    __syncthreads();
    {
        float acc = fc2_b[tid];
        const float* w = fc2_w + (size_t)tid * FH_;
        for (int k = 0; k < FH_; ++k) acc += x2[k] * w[k];
        x3[tid] = fmaxf(acc, 0.f);
    }
    __syncthreads();
    if (tid < NC_) {
        float acc = fcf_b[tid];
        const float* w = fcf_w + (size_t)tid * FH_;
        for (int k = 0; k < FH_; ++k) acc += x3[k] * w[k];
        out[b * NC_ + tid] = acc;
    }
}

// ---------------------------------------------------------------------------
extern "C" void kernel_launch(void* const* d_in, const int* in_sizes, int n_in,
                              void* d_out, int out_size, void* d_ws, size_t ws_size,
                              hipStream_t stream) {
    const int*   sentence = (const int*)  d_in[0];
    const int*   text_len = (const int*)  d_in[4];
    const float* glove    = (const float*)d_in[10];
    const float* w_ih_f   = (const float*)d_in[11];
    const float* w_hh_f   = (const float*)d_in[12];
    const float* b_ih_f   = (const float*)d_in[13];
    const float* b_hh_f   = (const float*)d_in[14];
    const float* w_ih_b   = (const float*)d_in[15];
    const float* w_hh_b   = (const float*)d_in[16];
    const float* b_ih_b   = (const float*)d_in[17];
    const float* b_hh_b   = (const float*)d_in[18];
    const float* gat_w    = (const float*)d_in[19];
    const float* gat_b    = (const float*)d_in[20];
    const float* fc1_w    = (const float*)d_in[21];
    const float* fc1_b    = (const float*)d_in[22];
    const float* fc2_w    = (const float*)d_in[23];
    const float* fc2_b    = (const float*)d_in[24];
    const float* fcf_w    = (const float*)d_in[25];
    const float* fcf_b    = (const float*)d_in[26];
    float* out = (float*)d_out;

    // Workspace: [hbuf 128K | cnt 4K | pad to 1M] [xproj 64M] [S]
    ushort_t* hbuf  = (ushort_t*)d_ws;
    int*      cnt   = (int*)((char*)d_ws + 131072);
    float*    xproj = (float*)((char*)d_ws + (1 << 20));
    float*    S     = xproj + (size_t)8192 * 2048;

    k_init<<<(INIT_U32 + 255) / 256, 256, 0, stream>>>((unsigned*)d_ws);
    dim3 g1(8192 / BM, N2 / BN);
    k_xproj<<<g1, 256, 0, stream>>>(sentence, glove, w_ih_f, w_ih_b,
                                    b_ih_f, b_hh_f, b_ih_b, b_hh_b, xproj);
    k_lstm_sync<<<64, 256, 0, stream>>>(xproj, w_hh_f, w_hh_b, text_len,
                                        hbuf, cnt, S);
    k_head<<<64, 256, 0, stream>>>(S, text_len, gat_w, gat_b,
                                   fc1_w, fc1_b, fc2_w, fc2_b,
                                   fcf_w, fcf_b, out);
}

// Round 4
// 789.916 us; speedup vs baseline: 2.1020x; 1.3803x over previous
//
#include <hip/hip_runtime.h>
#include <hip/hip_bf16.h>
#include <math.h>

// Problem constants
#define B_  64
#define T_  128
#define E_  300
#define H_  256      // hidden per direction
#define G4  1024     // 4*H
#define N2  2048     // both directions' gates
#define GG  512      // G = 2H
#define FH_ 256
#define NC_ 2
#define KP  320      // E padded to multiple of 32

typedef __attribute__((ext_vector_type(8))) short short8;
typedef __attribute__((ext_vector_type(4))) float f32x4;
typedef unsigned short ushort_t;
typedef unsigned long long u64;

static __device__ __forceinline__ ushort_t bf16bits(float x) {
    __hip_bfloat16 b = __float2bfloat16(x);
    return __builtin_bit_cast(ushort_t, b);
}
static __device__ __forceinline__ float bf16lo(unsigned v) {
    return __builtin_bit_cast(float, v << 16);
}
static __device__ __forceinline__ float bf16hi(unsigned v) {
    return __builtin_bit_cast(float, v & 0xffff0000u);
}

// ---------------------------------------------------------------------------
// Workspace layout (bytes):
//   0        : hbuf   (2 parity x 8 group x 16 batch x 256 k) bf16 = 131072
//   131072   : cnt    (8 group x 8 slice) int                      = 256
//   262144   : bias2  (2048 f32)                                   = 8192
//   1048576  : wihshuf(128 ntile x 10 ks x 64 lane x 8) bf16       = 1310720
//   2621440  : xemb   (8192 x 320) bf16                            = 5242880
//   8388608  : xprojb (8192 x 2048) bf16                           = 33554432
//   41943040 : S      (64 x 512) f32                               = 131072
// ---------------------------------------------------------------------------
#define OFF_CNT   131072
#define OFF_BIAS  262144
#define OFF_WIH   1048576
#define OFF_XEMB  2621440
#define OFF_XPROJ 8388608
#define OFF_S     41943040
#define INIT_U32  ((131072 + 256) / 4)

__global__ void k_init(unsigned* __restrict__ p) {
    int i = blockIdx.x * 256 + threadIdx.x;
    if (i < INIT_U32) p[i] = 0;
}

// ---------------------------------------------------------------------------
// K_emb: gather glove rows -> xemb bf16 (8192 x 320), pad k>=300 with 0.
// ---------------------------------------------------------------------------
__global__ __launch_bounds__(256) void k_emb(
    const int*   __restrict__ sentence,
    const float* __restrict__ glove,
    ushort_t*    __restrict__ xemb) {
    const int idx = blockIdx.x * 256 + threadIdx.x;   // 0..655359
    const int m  = idx / 80;
    const int c4 = (idx % 80) * 4;
    const float* row = glove + (size_t)sentence[m] * E_;
    ushort_t o[4];
    #pragma unroll
    for (int j = 0; j < 4; ++j) {
        const int k = c4 + j;
        o[j] = (k < E_) ? bf16bits(row[k]) : (ushort_t)0;
    }
    uint2 pk;
    pk.x = (unsigned)o[0] | ((unsigned)o[1] << 16);
    pk.y = (unsigned)o[2] | ((unsigned)o[3] << 16);
    *(uint2*)(xemb + (size_t)m * KP + c4) = pk;
}

// ---------------------------------------------------------------------------
// K_wih: shuffle w_ih (2 x 1024 x 300) -> bf16 B-frag stream order,
// layout [ntile(128)][ks(10)][lane(64)][8], K padded to 320.
// frag: n = ntile*16 + (lane&15), k = ks*32 + (lane>>4)*8 + j.
// ---------------------------------------------------------------------------
__global__ __launch_bounds__(256) void k_wih(
    const float* __restrict__ w_ih_f,
    const float* __restrict__ w_ih_b,
    ushort_t*    __restrict__ wihshuf) {
    const int p = blockIdx.x * 256 + threadIdx.x;     // 0..81919
    const int ntile = p / 640;
    const int r     = p % 640;
    const int ks    = r / 64;
    const int lane  = r % 64;
    const int n  = ntile * 16 + (lane & 15);
    const int k0 = ks * 32 + ((lane >> 4) << 3);
    const float* src = (n < G4) ? (w_ih_f + (size_t)n * E_)
                                : (w_ih_b + (size_t)(n - G4) * E_);
    ushort_t o[8];
    #pragma unroll
    for (int j = 0; j < 8; ++j) {
        const int k = k0 + j;
        o[j] = (k < E_) ? bf16bits(src[k]) : (ushort_t)0;
    }
    uint4 pk;
    pk.x = (unsigned)o[0] | ((unsigned)o[1] << 16);
    pk.y = (unsigned)o[2] | ((unsigned)o[3] << 16);
    pk.z = (unsigned)o[4] | ((unsigned)o[5] << 16);
    pk.w = (unsigned)o[6] | ((unsigned)o[7] << 16);
    *(uint4*)(wihshuf + (size_t)p * 8) = pk;
}

// ---------------------------------------------------------------------------
// K_bias: bias2[n] = b_ih + b_hh (per direction), 2048 f32.
// ---------------------------------------------------------------------------
__global__ void k_bias(const float* __restrict__ b_ih_f, const float* __restrict__ b_hh_f,
                       const float* __restrict__ b_ih_b, const float* __restrict__ b_hh_b,
                       float* __restrict__ bias2) {
    const int n = blockIdx.x * 256 + threadIdx.x;
    bias2[n] = (n < G4) ? (b_ih_f[n] + b_hh_f[n])
                        : (b_ih_b[n - G4] + b_hh_b[n - G4]);
}

// ---------------------------------------------------------------------------
// K1: xproj GEMM via bf16 MFMA, LDS-free. grid (128,16) x 256 threads.
// Wave w: m-tile rows m0 = bx*64 + w*16; all waves share 8 n-tiles of by.
// C = xemb(8192x320) @ wih^T -> xprojb bf16 (8192x2048), bias folded.
// ---------------------------------------------------------------------------
__global__ __launch_bounds__(256) void k_xproj_mfma(
    const ushort_t* __restrict__ xemb,
    const ushort_t* __restrict__ wihshuf,
    const float*    __restrict__ bias2,
    ushort_t*       __restrict__ xprojb) {
    const int tid = threadIdx.x;
    const int wave = tid >> 6, lane = tid & 63;
    const int quad = lane >> 4, l15 = lane & 15;
    const int m0 = blockIdx.x * 64 + wave * 16;
    const ushort_t* ap = xemb + (size_t)(m0 + l15) * KP;
    const ushort_t* wp = wihshuf + (size_t)blockIdx.y * 8 * 5120 + lane * 8;

    f32x4 acc[8] = {};
    #pragma unroll
    for (int ks = 0; ks < 10; ++ks) {
        short8 af = *(const short8*)(ap + ks * 32 + quad * 8);
        #pragma unroll
        for (int j = 0; j < 8; ++j) {
            short8 bf = *(const short8*)(wp + (size_t)(j * 10 + ks) * 512);
            acc[j] = __builtin_amdgcn_mfma_f32_16x16x32_bf16(af, bf, acc[j], 0, 0, 0);
        }
    }
    // C layout: row m = m0 + quad*4 + r, col n = by*128 + j*16 + l15
    #pragma unroll
    for (int j = 0; j < 8; ++j) {
        const int n = blockIdx.y * 128 + j * 16 + l15;
        const float bias = bias2[n];
        #pragma unroll
        for (int r = 0; r < 4; ++r) {
            const int m = m0 + quad * 4 + r;
            xprojb[(size_t)m * N2 + n] = bf16bits(acc[j][r] + bias);
        }
    }
}

// ---------------------------------------------------------------------------
// K2: BiLSTM, W register-resident, 8-way gate split, RELAXED-atomic sync.
// 64 blocks x 256 threads; group g = blockIdx&7 = (dir, 16-batch group);
// slice = blockIdx>>3 owns h cells [slice*32, slice*32+32).
// All cross-block traffic (h, flags) via relaxed agent-scope atomics:
// coherent sc0/sc1 accesses to LLC, NO buffer_inv / buffer_wbl2.
// Ordering: h stores -> __syncthreads (vmcnt drain) -> flag store.
// ---------------------------------------------------------------------------
__global__ __launch_bounds__(256, 1) void k_lstm_sync(
    const ushort_t* __restrict__ xprojb,   // (64,128,2048) bf16
    const float*    __restrict__ w_hh_f,   // (1024,256) f32
    const float*    __restrict__ w_hh_b,
    const int*      __restrict__ text_len,
    ushort_t*       __restrict__ hbuf,     // (2,8,16,256) bf16
    int*            __restrict__ cnt,      // (8,8) steps completed
    float*          __restrict__ S)        // (64,512)
{
    __shared__ float gLDS[4 * 16 * 33];    // [gate][batch][cell+pad]

    const int tid   = threadIdx.x;
    const int g     = blockIdx.x & 7;
    const int slice = blockIdx.x >> 3;
    const int d     = g & 1;
    const int b0    = (g >> 1) * 16;
    const int j0    = slice * 32;
    const int wave  = tid >> 6, lane = tid & 63;
    const int quad  = lane >> 4, l15 = lane & 15;

    const float* whh = d ? w_hh_b : w_hh_f;
    int* cnt_g = cnt + g * 8;

    // ---- preload W B-frags into registers (once) ----
    short8 wfrag[2][8];
    #pragma unroll
    for (int u = 0; u < 2; ++u) {
        const int n = wave * 256 + j0 + u * 16 + l15;
        #pragma unroll
        for (int ks = 0; ks < 8; ++ks) {
            const float* p = whh + (size_t)n * 256 + ks * 32 + quad * 8;
            float4 lo = *(const float4*)p;
            float4 hi = *(const float4*)(p + 4);
            short8 f;
            f[0] = (short)bf16bits(lo.x); f[1] = (short)bf16bits(lo.y);
            f[2] = (short)bf16bits(lo.z); f[3] = (short)bf16bits(lo.w);
            f[4] = (short)bf16bits(hi.x); f[5] = (short)bf16bits(hi.y);
            f[6] = (short)bf16bits(hi.z); f[7] = (short)bf16bits(hi.w);
            wfrag[u][ks] = f;
        }
    }

    // cell-update assignment: batch mb, cells c0,c0+1 (within slice)
    const int mb = tid >> 4;
    const int c0 = (tid & 15) * 2;
    const int lenm = text_len[b0 + mb];
    float cst0 = 0.f, cst1 = 0.f, s0 = 0.f, s1 = 0.f;

    for (int t = 0; t < T_; ++t) {
        const int tt = d ? (T_ - 1 - t) : t;
        // prefetch xproj (bf16) before the spin — independent of h
        const ushort_t* xp = xprojb +
            ((size_t)(b0 + mb) * T_ + tt) * N2 + d * G4 + j0;
        const unsigned vi = *(const unsigned*)(xp + c0);
        const unsigned vf = *(const unsigned*)(xp + 256 + c0);
        const unsigned vg = *(const unsigned*)(xp + 512 + c0);
        const unsigned vo = *(const unsigned*)(xp + 768 + c0);

        if (t > 0 && wave == 0 && lane < 8) {
            while (__hip_atomic_load(&cnt_g[lane], __ATOMIC_RELAXED,
                                     __HIP_MEMORY_SCOPE_AGENT) < t) {}
        }
        __syncthreads();

        // ---- A-frags: h_{t-1} from hbuf[t&1] via relaxed coherent loads ----
        const u64* hin64 = (const u64*)(hbuf + (size_t)(t & 1) * 32768 +
                                        g * 4096 + l15 * 256);
        short8 af[8];
        #pragma unroll
        for (int ks = 0; ks < 8; ++ks) {
            union { u64 u[2]; short8 v; } cv;
            cv.u[0] = __hip_atomic_load(hin64 + ks * 8 + quad * 2,
                                        __ATOMIC_RELAXED, __HIP_MEMORY_SCOPE_AGENT);
            cv.u[1] = __hip_atomic_load(hin64 + ks * 8 + quad * 2 + 1,
                                        __ATOMIC_RELAXED, __HIP_MEMORY_SCOPE_AGENT);
            af[ks] = cv.v;
        }
        f32x4 acc[2] = {};
        #pragma unroll
        for (int ks = 0; ks < 8; ++ks) {
            acc[0] = __builtin_amdgcn_mfma_f32_16x16x32_bf16(
                af[ks], wfrag[0][ks], acc[0], 0, 0, 0);
            acc[1] = __builtin_amdgcn_mfma_f32_16x16x32_bf16(
                af[ks], wfrag[1][ks], acc[1], 0, 0, 0);
        }
        // C layout: row(batch)=quad*4+r, col=l15
        #pragma unroll
        for (int u = 0; u < 2; ++u)
            #pragma unroll
            for (int r = 0; r < 4; ++r)
                gLDS[wave * 528 + (quad * 4 + r) * 33 + u * 16 + l15] = acc[u][r];
        __syncthreads();

        // ---- cell update for (mb, c0..c0+1) ----
        const int gb = mb * 33 + c0;
        const float gi0 = gLDS[gb],        gi1 = gLDS[gb + 1];
        const float gf0 = gLDS[528 + gb],  gf1 = gLDS[528 + gb + 1];
        const float gg0 = gLDS[1056 + gb], gg1 = gLDS[1056 + gb + 1];
        const float go0 = gLDS[1584 + gb], go1 = gLDS[1584 + gb + 1];
        const float i0 = 1.f / (1.f + __expf(-(bf16lo(vi) + gi0)));
        const float i1 = 1.f / (1.f + __expf(-(bf16hi(vi) + gi1)));
        const float f0 = 1.f / (1.f + __expf(-(bf16lo(vf) + gf0)));
        const float f1 = 1.f / (1.f + __expf(-(bf16hi(vf) + gf1)));
        const float gc0 = tanhf(bf16lo(vg) + gg0);
        const float gc1 = tanhf(bf16hi(vg) + gg1);
        const float o0 = 1.f / (1.f + __expf(-(bf16lo(vo) + go0)));
        const float o1 = 1.f / (1.f + __expf(-(bf16hi(vo) + go1)));
        cst0 = f0 * cst0 + i0 * gc0;
        cst1 = f1 * cst1 + i1 * gc1;
        const float h0 = o0 * tanhf(cst0);
        const float h1 = o1 * tanhf(cst1);
        if (tt < lenm) { s0 += h0; s1 += h1; }

        // h_t -> hbuf[(t+1)&1] via relaxed coherent store
        unsigned* hout = (unsigned*)(hbuf + (size_t)((t + 1) & 1) * 32768 +
                                     g * 4096 + mb * 256 + j0 + c0);
        const unsigned hp = (unsigned)bf16bits(h0) | ((unsigned)bf16bits(h1) << 16);
        __hip_atomic_store(hout, hp, __ATOMIC_RELAXED, __HIP_MEMORY_SCOPE_AGENT);
        __syncthreads();   // drains vmcnt: all h stores acked at LLC
        if (tid == 0)
            __hip_atomic_store(&cnt_g[slice], t + 1, __ATOMIC_RELAXED,
                               __HIP_MEMORY_SCOPE_AGENT);
    }

    float2 sv; sv.x = s0; sv.y = s1;
    *(float2*)(S + (size_t)(b0 + mb) * GG + d * H_ + j0 + c0) = sv;
}

// ---------------------------------------------------------------------------
// K3: head (unchanged).
// ---------------------------------------------------------------------------
__global__ __launch_bounds__(256) void k_head(
    const float* __restrict__ S,
    const int*   __restrict__ text_len,
    const float* __restrict__ gat_w, const float* __restrict__ gat_b,
    const float* __restrict__ fc1_w, const float* __restrict__ fc1_b,
    const float* __restrict__ fc2_w, const float* __restrict__ fc2_b,
    const float* __restrict__ fcf_w, const float* __restrict__ fcf_b,
    float* __restrict__ out)
{
    __shared__ float sb[GG];
    __shared__ float x1[GG];
    __shared__ float x2[FH_];
    __shared__ float x3[FH_];
    const int b = blockIdx.x, tid = threadIdx.x;
    sb[tid]       = S[(size_t)b * GG + tid];
    sb[tid + 256] = S[(size_t)b * GG + tid + 256];
    __syncthreads();
    const float lenf = (float)text_len[b];
    #pragma unroll
    for (int r = 0; r < 2; ++r) {
        const int n = tid + r * 256;
        float acc = gat_b[n] * lenf;
        const float* w = gat_w + (size_t)n * GG;
        for (int k = 0; k < GG; ++k) acc += sb[k] * w[k];
        x1[n] = fmaxf(acc, 0.f);
    }
    __syncthreads();
    {
        float acc = fc1_b[tid];
        const float* w = fc1_w + (size_t)tid * GG;
        for (int k = 0; k < GG; ++k) acc += x1[k] * w[k];
        x2[tid] = fmaxf(acc, 0.f);
    }
    __syncthreads();
    {
        float acc = fc2_b[tid];
        const float* w = fc2_w + (size_t)tid * FH_;
        for (int k = 0; k < FH_; ++k) acc += x2[k] * w[k];
        x3[tid] = fmaxf(acc, 0.f);
    }
    __syncthreads();
    if (tid < NC_) {
        float acc = fcf_b[tid];
        const float* w = fcf_w + (size_t)tid * FH_;
        for (int k = 0; k < FH_; ++k) acc += x3[k] * w[k];
        out[b * NC_ + tid] = acc;
    }
}

// ---------------------------------------------------------------------------
extern "C" void kernel_launch(void* const* d_in, const int* in_sizes, int n_in,
                              void* d_out, int out_size, void* d_ws, size_t ws_size,
                              hipStream_t stream) {
    const int*   sentence = (const int*)  d_in[0];
    const int*   text_len = (const int*)  d_in[4];
    const float* glove    = (const float*)d_in[10];
    const float* w_ih_f   = (const float*)d_in[11];
    const float* w_hh_f   = (const float*)d_in[12];
    const float* b_ih_f   = (const float*)d_in[13];
    const float* b_hh_f   = (const float*)d_in[14];
    const float* w_ih_b   = (const float*)d_in[15];
    const float* w_hh_b   = (const float*)d_in[16];
    const float* b_ih_b   = (const float*)d_in[17];
    const float* b_hh_b   = (const float*)d_in[18];
    const float* gat_w    = (const float*)d_in[19];
    const float* gat_b    = (const float*)d_in[20];
    const float* fc1_w    = (const float*)d_in[21];
    const float* fc1_b    = (const float*)d_in[22];
    const float* fc2_w    = (const float*)d_in[23];
    const float* fc2_b    = (const float*)d_in[24];
    const float* fcf_w    = (const float*)d_in[25];
    const float* fcf_b    = (const float*)d_in[26];
    float* out = (float*)d_out;

    char* ws = (char*)d_ws;
    ushort_t* hbuf    = (ushort_t*)ws;
    int*      cnt     = (int*)(ws + OFF_CNT);
    float*    bias2   = (float*)(ws + OFF_BIAS);
    ushort_t* wihshuf = (ushort_t*)(ws + OFF_WIH);
    ushort_t* xemb    = (ushort_t*)(ws + OFF_XEMB);
    ushort_t* xprojb  = (ushort_t*)(ws + OFF_XPROJ);
    float*    S       = (float*)(ws + OFF_S);

    k_init<<<(INIT_U32 + 255) / 256, 256, 0, stream>>>((unsigned*)d_ws);
    k_emb<<<2560, 256, 0, stream>>>(sentence, glove, xemb);
    k_wih<<<320, 256, 0, stream>>>(w_ih_f, w_ih_b, wihshuf);
    k_bias<<<8, 256, 0, stream>>>(b_ih_f, b_hh_f, b_ih_b, b_hh_b, bias2);
    dim3 gx(128, 16);
    k_xproj_mfma<<<gx, 256, 0, stream>>>(xemb, wihshuf, bias2, xprojb);
    k_lstm_sync<<<64, 256, 0, stream>>>(xprojb, w_hh_f, w_hh_b, text_len,
                                        hbuf, cnt, S);
    k_head<<<64, 256, 0, stream>>>(S, text_len, gat_w, gat_b,
                                   fc1_w, fc1_b, fc2_w, fc2_b,
                                   fcf_w, fcf_b, out);
}

// Round 5
// 746.131 us; speedup vs baseline: 2.2254x; 1.0587x over previous
//
#include <hip/hip_runtime.h>
#include <hip/hip_bf16.h>
#include <math.h>

// Problem constants
#define B_  64
#define T_  128
#define E_  300
#define H_  256      // hidden per direction
#define G4  1024     // 4*H
#define N2  2048     // both directions' gates
#define GG  512      // G = 2H
#define FH_ 256
#define NC_ 2
#define KP  320      // E padded to multiple of 32

typedef __attribute__((ext_vector_type(8))) short short8;
typedef __attribute__((ext_vector_type(4))) float f32x4;
typedef unsigned short ushort_t;
typedef unsigned long long u64;

static __device__ __forceinline__ ushort_t bf16bits(float x) {
    __hip_bfloat16 b = __float2bfloat16(x);
    return __builtin_bit_cast(ushort_t, b);
}
static __device__ __forceinline__ float bf16lo(unsigned v) {
    return __builtin_bit_cast(float, v << 16);
}
static __device__ __forceinline__ float bf16hi(unsigned v) {
    return __builtin_bit_cast(float, v & 0xffff0000u);
}

// ---------------------------------------------------------------------------
// Workspace layout (bytes):
//   0        : hbuf  u64[2 parity][8 group][16 batch][128 word]   = 262144
//   262144   : bias2 (2048 f32)                                    = 8192
//   524288   : wihshuf (128 ntile x 10 ks x 64 lane x 8) bf16      = 1310720
//   2097152  : xemb  (8192 x 320) bf16                             = 5242880
//   8388608  : xprojb (8192 x 2048) bf16                           = 33554432
//   41943040 : S     (64 x 512) f32                                = 131072
// h-word: [tag:32 | h_odd:bf16 | h_even:bf16]. tag = step index of the h
// state (hs_0 = initial zeros, tag 0, written by k_prep). Harness poison
// 0xAAAAAAAA can never equal a tag (tags are 0..128).
// ---------------------------------------------------------------------------
#define OFF_BIAS  262144
#define OFF_WIH   524288
#define OFF_XEMB  2097152
#define OFF_XPROJ 8388608
#define OFF_S     41943040

// ---------------------------------------------------------------------------
// K_prep: fused (a) zero parity-0 hbuf (16384 u64), (b) bias2, (c) w_ih
// shuffle to B-frag order, (d) embedding gather -> xemb bf16.
// Grid 2560 x 256 (emb range dominates).
// ---------------------------------------------------------------------------
__global__ __launch_bounds__(256) void k_prep(
    const int*   __restrict__ sentence,
    const float* __restrict__ glove,
    const float* __restrict__ w_ih_f,
    const float* __restrict__ w_ih_b,
    const float* __restrict__ b_ih_f, const float* __restrict__ b_hh_f,
    const float* __restrict__ b_ih_b, const float* __restrict__ b_hh_b,
    u64*         __restrict__ hbuf,
    float*       __restrict__ bias2,
    ushort_t*    __restrict__ wihshuf,
    ushort_t*    __restrict__ xemb) {
    const int idx = blockIdx.x * 256 + threadIdx.x;   // 0..655359

    // (a) zero parity-0 h words (tag 0 = initial h state)
    if (idx < 16384) hbuf[idx] = 0ull;

    // (b) bias2[n] = b_ih + b_hh
    if (idx < N2) {
        bias2[idx] = (idx < G4) ? (b_ih_f[idx] + b_hh_f[idx])
                                : (b_ih_b[idx - G4] + b_hh_b[idx - G4]);
    }

    // (c) w_ih shuffle: p in [0,81920)
    if (idx < 81920) {
        const int ntile = idx / 640;
        const int r     = idx % 640;
        const int ks    = r / 64;
        const int lane  = r % 64;
        const int n  = ntile * 16 + (lane & 15);
        const int k0 = ks * 32 + ((lane >> 4) << 3);
        const float* src = (n < G4) ? (w_ih_f + (size_t)n * E_)
                                    : (w_ih_b + (size_t)(n - G4) * E_);
        ushort_t o[8];
        #pragma unroll
        for (int j = 0; j < 8; ++j) {
            const int k = k0 + j;
            o[j] = (k < E_) ? bf16bits(src[k]) : (ushort_t)0;
        }
        uint4 pk;
        pk.x = (unsigned)o[0] | ((unsigned)o[1] << 16);
        pk.y = (unsigned)o[2] | ((unsigned)o[3] << 16);
        pk.z = (unsigned)o[4] | ((unsigned)o[5] << 16);
        pk.w = (unsigned)o[6] | ((unsigned)o[7] << 16);
        *(uint4*)(wihshuf + (size_t)idx * 8) = pk;
    }

    // (d) embedding gather -> xemb bf16 (all threads)
    {
        const int m  = idx / 80;
        const int c4 = (idx % 80) * 4;
        const float* row = glove + (size_t)sentence[m] * E_;
        ushort_t o[4];
        #pragma unroll
        for (int j = 0; j < 4; ++j) {
            const int k = c4 + j;
            o[j] = (k < E_) ? bf16bits(row[k]) : (ushort_t)0;
        }
        uint2 pk;
        pk.x = (unsigned)o[0] | ((unsigned)o[1] << 16);
        pk.y = (unsigned)o[2] | ((unsigned)o[3] << 16);
        *(uint2*)(xemb + (size_t)m * KP + c4) = pk;
    }
}

// ---------------------------------------------------------------------------
// K1: xproj GEMM via bf16 MFMA, LDS-free K-loop + LDS-transpose epilogue
// for coalesced 1KB stores. grid (128,16) x 256 threads.
// ---------------------------------------------------------------------------
__global__ __launch_bounds__(256) void k_xproj_mfma(
    const ushort_t* __restrict__ xemb,
    const ushort_t* __restrict__ wihshuf,
    const float*    __restrict__ bias2,
    ushort_t*       __restrict__ xprojb) {
    __shared__ ushort_t ct[4][16][136];   // per-wave C tile, row pad +8
    const int tid = threadIdx.x;
    const int wave = tid >> 6, lane = tid & 63;
    const int quad = lane >> 4, l15 = lane & 15;
    const int m0 = blockIdx.x * 64 + wave * 16;
    const ushort_t* ap = xemb + (size_t)(m0 + l15) * KP;
    const ushort_t* wp = wihshuf + (size_t)blockIdx.y * 40960 + lane * 8;

    f32x4 acc[8] = {};
    #pragma unroll
    for (int ks = 0; ks < 10; ++ks) {
        short8 af = *(const short8*)(ap + ks * 32 + quad * 8);
        #pragma unroll
        for (int j = 0; j < 8; ++j) {
            short8 bf = *(const short8*)(wp + (size_t)(j * 10 + ks) * 512);
            acc[j] = __builtin_amdgcn_mfma_f32_16x16x32_bf16(af, bf, acc[j], 0, 0, 0);
        }
    }
    // C layout: row m = quad*4 + r, col n = j*16 + l15 -> stage in LDS
    #pragma unroll
    for (int j = 0; j < 8; ++j) {
        const float bias = bias2[blockIdx.y * 128 + j * 16 + l15];
        #pragma unroll
        for (int r = 0; r < 4; ++r)
            ct[wave][quad * 4 + r][j * 16 + l15] = bf16bits(acc[j][r] + bias);
    }
    // coalesced store: instr i covers rows [i*4, i*4+4), 16 lanes x 16B per row
    #pragma unroll
    for (int i = 0; i < 4; ++i) {
        const int row = i * 4 + (lane >> 4);
        uint4 v = *(const uint4*)&ct[wave][row][l15 * 8];
        *(uint4*)(xprojb + (size_t)(m0 + row) * N2 + blockIdx.y * 128 + l15 * 8) = v;
    }
}

// ---------------------------------------------------------------------------
// K2: BiLSTM, W register-resident, 8-way gate split, TAG-IN-DATA sync.
// 64 blocks x 256 threads; group g = blockIdx&7 = (dir, 16-batch group);
// slice = blockIdx>>3 owns h cells [slice*32, slice*32+32).
// Cross-block h exchange: one relaxed agent-scope 8B atomic per h-pair,
// step tag packed in the same word -> no fences, no flags, no drains.
// Wave 0 polls+stages h to LDS; all waves MFMA from LDS.
// ---------------------------------------------------------------------------
__global__ __launch_bounds__(256, 1) void k_lstm_sync(
    const ushort_t* __restrict__ xprojb,   // (64,128,2048) bf16
    const float*    __restrict__ w_hh_f,   // (1024,256) f32
    const float*    __restrict__ w_hh_b,
    const int*      __restrict__ text_len,
    u64*            __restrict__ hbuf,     // [2][8][16][128] tagged words
    float*          __restrict__ S)        // (64,512)
{
    __shared__ ushort_t hl[16][264];       // staged h bf16 [batch][k]
    __shared__ float    gLDS[4 * 16 * 33]; // [gate][batch][cell+pad]

    const int tid   = threadIdx.x;
    const int g     = blockIdx.x & 7;
    const int slice = blockIdx.x >> 3;
    const int d     = g & 1;
    const int b0    = (g >> 1) * 16;
    const int j0    = slice * 32;
    const int wave  = tid >> 6, lane = tid & 63;
    const int quad  = lane >> 4, l15 = lane & 15;

    const float* whh = d ? w_hh_b : w_hh_f;
    u64* slab0 = hbuf + (size_t)g * 2048;          // parity 0
    u64* slab1 = hbuf + 16384 + (size_t)g * 2048;  // parity 1

    // ---- preload W B-frags into registers (once) ----
    short8 wfrag[2][8];
    #pragma unroll
    for (int u = 0; u < 2; ++u) {
        const int n = wave * 256 + j0 + u * 16 + l15;
        #pragma unroll
        for (int ks = 0; ks < 8; ++ks) {
            const float* p = whh + (size_t)n * 256 + ks * 32 + quad * 8;
            float4 lo = *(const float4*)p;
            float4 hi = *(const float4*)(p + 4);
            short8 f;
            f[0] = (short)bf16bits(lo.x); f[1] = (short)bf16bits(lo.y);
            f[2] = (short)bf16bits(lo.z); f[3] = (short)bf16bits(lo.w);
            f[4] = (short)bf16bits(hi.x); f[5] = (short)bf16bits(hi.y);
            f[6] = (short)bf16bits(hi.z); f[7] = (short)bf16bits(hi.w);
            wfrag[u][ks] = f;
        }
    }

    // poll assignment (wave 0): batch = lane&15, part = lane>>4 -> 32 words
    // producer assignment: batch mb = tid>>4, cells c0,c0+1; word slice*16+(tid&15)
    const int mb = tid >> 4;
    const int wi = mb * 128 + slice * 16 + (tid & 15);
    const int c0 = (tid & 15) * 2;
    const int lenm = text_len[b0 + mb];
    float cst0 = 0.f, cst1 = 0.f, s0 = 0.f, s1 = 0.f;

    for (int t = 0; t < T_; ++t) {
        const int tt = d ? (T_ - 1 - t) : t;
        // prefetch xproj (bf16) — independent of h
        const ushort_t* xp = xprojb +
            ((size_t)(b0 + mb) * T_ + tt) * N2 + d * G4 + j0;
        const unsigned vi = *(const unsigned*)(xp + c0);
        const unsigned vf = *(const unsigned*)(xp + 256 + c0);
        const unsigned vg = *(const unsigned*)(xp + 512 + c0);
        const unsigned vo = *(const unsigned*)(xp + 768 + c0);

        // ---- wave 0: poll tagged h words, stage payload to LDS ----
        if (wave == 0) {
            const u64* src = ((t & 1) ? slab1 : slab0) +
                             (lane & 15) * 128 + (lane >> 4) * 32;
            u64 v[32];
            bool ok = false;
            while (!ok) {
                ok = true;
                #pragma unroll
                for (int i = 0; i < 32; ++i)
                    v[i] = __hip_atomic_load(src + i, __ATOMIC_RELAXED,
                                             __HIP_MEMORY_SCOPE_AGENT);
                #pragma unroll
                for (int i = 0; i < 32; ++i)
                    ok = ok && ((unsigned)(v[i] >> 32) == (unsigned)t);
            }
            ushort_t* drow = &hl[lane & 15][(lane >> 4) * 64];
            #pragma unroll
            for (int i = 0; i < 16; ++i) {
                uint2 pk;
                pk.x = (unsigned)v[2 * i];
                pk.y = (unsigned)v[2 * i + 1];
                *(uint2*)(drow + i * 4) = pk;
            }
        }
        __syncthreads();   // B1: hl ready; also fences gLDS reuse

        // ---- all waves: A-frags from LDS, MFMA ----
        short8 af[8];
        #pragma unroll
        for (int ks = 0; ks < 8; ++ks)
            af[ks] = *(const short8*)&hl[l15][ks * 32 + quad * 8];
        f32x4 acc[2] = {};
        #pragma unroll
        for (int ks = 0; ks < 8; ++ks) {
            acc[0] = __builtin_amdgcn_mfma_f32_16x16x32_bf16(
                af[ks], wfrag[0][ks], acc[0], 0, 0, 0);
            acc[1] = __builtin_amdgcn_mfma_f32_16x16x32_bf16(
                af[ks], wfrag[1][ks], acc[1], 0, 0, 0);
        }
        // C layout: row(batch)=quad*4+r, col=l15
        #pragma unroll
        for (int u = 0; u < 2; ++u)
            #pragma unroll
            for (int r = 0; r < 4; ++r)
                gLDS[wave * 528 + (quad * 4 + r) * 33 + u * 16 + l15] = acc[u][r];
        __syncthreads();   // B2: gates ready; also fences hl reuse

        // ---- cell update for (mb, c0..c0+1) ----
        const int gb = mb * 33 + c0;
        const float gi0 = gLDS[gb],        gi1 = gLDS[gb + 1];
        const float gf0 = gLDS[528 + gb],  gf1 = gLDS[528 + gb + 1];
        const float gg0 = gLDS[1056 + gb], gg1 = gLDS[1056 + gb + 1];
        const float go0 = gLDS[1584 + gb], go1 = gLDS[1584 + gb + 1];
        const float i0 = 1.f / (1.f + __expf(-(bf16lo(vi) + gi0)));
        const float i1 = 1.f / (1.f + __expf(-(bf16hi(vi) + gi1)));
        const float f0 = 1.f / (1.f + __expf(-(bf16lo(vf) + gf0)));
        const float f1 = 1.f / (1.f + __expf(-(bf16hi(vf) + gf1)));
        const float gc0 = tanhf(bf16lo(vg) + gg0);
        const float gc1 = tanhf(bf16hi(vg) + gg1);
        const float o0 = 1.f / (1.f + __expf(-(bf16lo(vo) + go0)));
        const float o1 = 1.f / (1.f + __expf(-(bf16hi(vo) + go1)));
        cst0 = f0 * cst0 + i0 * gc0;
        cst1 = f1 * cst1 + i1 * gc1;
        const float h0 = o0 * tanhf(cst0);
        const float h1 = o1 * tanhf(cst1);
        if (tt < lenm) { s0 += h0; s1 += h1; }

        // publish h_{t+1}: tag+payload in ONE atomic word -> no fence needed
        const u64 word = ((u64)(unsigned)(t + 1) << 32) |
                         (u64)((unsigned)bf16bits(h0) |
                               ((unsigned)bf16bits(h1) << 16));
        u64* dst = ((t & 1) ? slab0 : slab1) + wi;
        __hip_atomic_store(dst, word, __ATOMIC_RELAXED,
                           __HIP_MEMORY_SCOPE_AGENT);
    }

    float2 sv; sv.x = s0; sv.y = s1;
    *(float2*)(S + (size_t)(b0 + mb) * GG + d * H_ + j0 + c0) = sv;
}

// ---------------------------------------------------------------------------
// K3: head (unchanged).
// ---------------------------------------------------------------------------
__global__ __launch_bounds__(256) void k_head(
    const float* __restrict__ S,
    const int*   __restrict__ text_len,
    const float* __restrict__ gat_w, const float* __restrict__ gat_b,
    const float* __restrict__ fc1_w, const float* __restrict__ fc1_b,
    const float* __restrict__ fc2_w, const float* __restrict__ fc2_b,
    const float* __restrict__ fcf_w, const float* __restrict__ fcf_b,
    float* __restrict__ out)
{
    __shared__ float sb[GG];
    __shared__ float x1[GG];
    __shared__ float x2[FH_];
    __shared__ float x3[FH_];
    const int b = blockIdx.x, tid = threadIdx.x;
    sb[tid]       = S[(size_t)b * GG + tid];
    sb[tid + 256] = S[(size_t)b * GG + tid + 256];
    __syncthreads();
    const float lenf = (float)text_len[b];
    #pragma unroll
    for (int r = 0; r < 2; ++r) {
        const int n = tid + r * 256;
        float acc = gat_b[n] * lenf;
        const float* w = gat_w + (size_t)n * GG;
        for (int k = 0; k < GG; ++k) acc += sb[k] * w[k];
        x1[n] = fmaxf(acc, 0.f);
    }
    __syncthreads();
    {
        float acc = fc1_b[tid];
        const float* w = fc1_w + (size_t)tid * GG;
        for (int k = 0; k < GG; ++k) acc += x1[k] * w[k];
        x2[tid] = fmaxf(acc, 0.f);
    }
    __syncthreads();
    {
        float acc = fc2_b[tid];
        const float* w = fc2_w + (size_t)tid * FH_;
        for (int k = 0; k < FH_; ++k) acc += x2[k] * w[k];
        x3[tid] = fmaxf(acc, 0.f);
    }
    __syncthreads();
    if (tid < NC_) {
        float acc = fcf_b[tid];
        const float* w = fcf_w + (size_t)tid * FH_;
        for (int k = 0; k < FH_; ++k) acc += x3[k] * w[k];
        out[b * NC_ + tid] = acc;
    }
}

// ---------------------------------------------------------------------------
extern "C" void kernel_launch(void* const* d_in, const int* in_sizes, int n_in,
                              void* d_out, int out_size, void* d_ws, size_t ws_size,
                              hipStream_t stream) {
    const int*   sentence = (const int*)  d_in[0];
    const int*   text_len = (const int*)  d_in[4];
    const float* glove    = (const float*)d_in[10];
    const float* w_ih_f   = (const float*)d_in[11];
    const float* w_hh_f   = (const float*)d_in[12];
    const float* b_ih_f   = (const float*)d_in[13];
    const float* b_hh_f   = (const float*)d_in[14];
    const float* w_ih_b   = (const float*)d_in[15];
    const float* w_hh_b   = (const float*)d_in[16];
    const float* b_ih_b   = (const float*)d_in[17];
    const float* b_hh_b   = (const float*)d_in[18];
    const float* gat_w    = (const float*)d_in[19];
    const float* gat_b    = (const float*)d_in[20];
    const float* fc1_w    = (const float*)d_in[21];
    const float* fc1_b    = (const float*)d_in[22];
    const float* fc2_w    = (const float*)d_in[23];
    const float* fc2_b    = (const float*)d_in[24];
    const float* fcf_w    = (const float*)d_in[25];
    const float* fcf_b    = (const float*)d_in[26];
    float* out = (float*)d_out;

    char* ws = (char*)d_ws;
    u64*      hbuf    = (u64*)ws;
    float*    bias2   = (float*)(ws + OFF_BIAS);
    ushort_t* wihshuf = (ushort_t*)(ws + OFF_WIH);
    ushort_t* xemb    = (ushort_t*)(ws + OFF_XEMB);
    ushort_t* xprojb  = (ushort_t*)(ws + OFF_XPROJ);
    float*    S       = (float*)(ws + OFF_S);

    k_prep<<<2560, 256, 0, stream>>>(sentence, glove, w_ih_f, w_ih_b,
                                     b_ih_f, b_hh_f, b_ih_b, b_hh_b,
                                     hbuf, bias2, wihshuf, xemb);
    dim3 gx(128, 16);
    k_xproj_mfma<<<gx, 256, 0, stream>>>(xemb, wihshuf, bias2, xprojb);
    k_lstm_sync<<<64, 256, 0, stream>>>(xprojb, w_hh_f, w_hh_b, text_len,
                                        hbuf, S);
    k_head<<<64, 256, 0, stream>>>(S, text_len, gat_w, gat_b,
                                   fc1_w, fc1_b, fc2_w, fc2_b,
                                   fcf_w, fcf_b, out);
}